// Round 1
// baseline (92.581 us; speedup 1.0000x reference)
//
#include <hip/hip_runtime.h>

#define KPK 15   // kernel points
#define CIN 3
#define COUT 32
#define NH 32    // neighbors per point
#define LPP 8    // lanes per point
#define HPL 4    // neighbors handled per lane (NH / LPP)

__global__ __launch_bounds__(256) void kpconv_kernel(
    const float* __restrict__ points,    // N*3
    const int*   __restrict__ nbr,       // N*NH
    const float* __restrict__ kpts,      // KPK*3
    const float* __restrict__ weights,   // KPK*CIN*COUT
    const float* __restrict__ bias,      // COUT
    float* __restrict__ out,             // N*COUT
    int n)
{
    __shared__ float  sW[KPK * CIN * COUT];
    __shared__ float4 sKC[KPK];
    __shared__ float  sB[COUT];

    // stage weights / folded kernel-point constants / bias in LDS
    for (int t = threadIdx.x; t < KPK * CIN * COUT; t += blockDim.x) sW[t] = weights[t];
    if (threadIdx.x < COUT) sB[threadIdx.x] = bias[threadIdx.x];
    if (threadIdx.x < KPK) {
        const float L2E = 1.44269504088896f;   // log2(e)
        float kx = kpts[threadIdx.x * 3 + 0];
        float ky = kpts[threadIdx.x * 3 + 1];
        float kz = kpts[threadIdx.x * 3 + 2];
        float ck = kx * kx + ky * ky + kz * kz;
        // influence = exp(-(|r|^2 - 2 r.kp + |kp|^2)/0.005)
        //           = exp2( C0*|r|^2 + (400*L2E)*r.kp + (-200*L2E)*|kp|^2 )
        sKC[threadIdx.x] = make_float4(400.0f * L2E * kx,
                                       400.0f * L2E * ky,
                                       400.0f * L2E * kz,
                                       -200.0f * L2E * ck);
    }
    __syncthreads();

    int gid = blockIdx.x * blockDim.x + threadIdx.x;
    int pt  = gid >> 3;        // point id
    int sub = gid & 7;         // lane-slice within the point
    if (pt >= n) return;

    float px = points[pt * 3 + 0];
    float py = points[pt * 3 + 1];
    float pz = points[pt * 3 + 2];

    // 4 contiguous neighbor indices per lane -> coalesced int4 load
    int4 idx = *reinterpret_cast<const int4*>(nbr + (size_t)pt * NH + sub * HPL);
    int js[HPL] = {idx.x, idx.y, idx.z, idx.w};

    float acc[KPK][CIN];
    #pragma unroll
    for (int k = 0; k < KPK; ++k) { acc[k][0] = 0.f; acc[k][1] = 0.f; acc[k][2] = 0.f; }

    const float C0 = -200.0f * 1.44269504088896f;   // -200*log2(e)

    #pragma unroll
    for (int t = 0; t < HPL; ++t) {
        int j = js[t];
        float qx = points[j * 3 + 0];
        float qy = points[j * 3 + 1];
        float qz = points[j * 3 + 2];
        float rx = qx - px, ry = qy - py, rz = qz - pz;
        float e0 = C0 * (rx * rx + ry * ry + rz * rz);
        #pragma unroll
        for (int k = 0; k < KPK; ++k) {
            float4 kc = sKC[k];
            float e = e0 + kc.w;
            e = fmaf(rx, kc.x, e);
            e = fmaf(ry, kc.y, e);
            e = fmaf(rz, kc.z, e);
            float infl = exp2f(e);
            // features are the neighbor coords themselves
            acc[k][0] = fmaf(infl, qx, acc[k][0]);
            acc[k][1] = fmaf(infl, qy, acc[k][1]);
            acc[k][2] = fmaf(infl, qz, acc[k][2]);
        }
    }

    // butterfly-reduce the 45 accumulators across the 8 lanes of this point
    #pragma unroll
    for (int m = 1; m < LPP; m <<= 1) {
        #pragma unroll
        for (int k = 0; k < KPK; ++k) {
            acc[k][0] += __shfl_xor(acc[k][0], m, 64);
            acc[k][1] += __shfl_xor(acc[k][1], m, 64);
            acc[k][2] += __shfl_xor(acc[k][2], m, 64);
        }
    }

    // epilogue: each lane produces 4 of the 32 outputs
    int d0 = sub * 4;
    float4 o = *reinterpret_cast<const float4*>(sB + d0);
    #pragma unroll
    for (int k = 0; k < KPK; ++k) {
        #pragma unroll
        for (int c = 0; c < CIN; ++c) {
            float a = acc[k][c];
            float4 w4 = *reinterpret_cast<const float4*>(sW + (k * CIN + c) * COUT + d0);
            o.x = fmaf(a, w4.x, o.x);
            o.y = fmaf(a, w4.y, o.y);
            o.z = fmaf(a, w4.z, o.z);
            o.w = fmaf(a, w4.w, o.w);
        }
    }
    *reinterpret_cast<float4*>(out + (size_t)pt * COUT + d0) = o;
}

extern "C" void kernel_launch(void* const* d_in, const int* in_sizes, int n_in,
                              void* d_out, int out_size, void* d_ws, size_t ws_size,
                              hipStream_t stream) {
    const float* points  = (const float*)d_in[0];
    const int*   nbr     = (const int*)d_in[1];
    const float* kpts    = (const float*)d_in[2];
    const float* weights = (const float*)d_in[3];
    const float* bias    = (const float*)d_in[4];
    float* out = (float*)d_out;

    int n = in_sizes[0] / 3;
    int total = n * LPP;
    int threads = 256;
    int blocks = (total + threads - 1) / threads;
    kpconv_kernel<<<blocks, threads, 0, stream>>>(points, nbr, kpts, weights, bias, out, n);
}

// Round 3
// 84.420 us; speedup vs baseline: 1.0967x; 1.0967x over previous
//
#include <hip/hip_runtime.h>

#define KPK 15   // kernel points
#define CIN 3
#define COUT 32
#define NH 32    // neighbors per point
#define LPP 4    // lanes per point
#define HPL 8    // neighbors handled per lane (NH / LPP)

__global__ __launch_bounds__(256) void kpconv_kernel(
    const float* __restrict__ points,    // N*3
    const int*   __restrict__ nbr,       // N*NH
    const float* __restrict__ kpts,      // KPK*3
    const float* __restrict__ weights,   // KPK*CIN*COUT
    const float* __restrict__ bias,      // COUT
    float* __restrict__ out,             // N*COUT
    int n)
{
    __shared__ float  sW[KPK * CIN * COUT];
    __shared__ float4 sKC[KPK];
    __shared__ float  sB[COUT];

    // stage weights / folded kernel-point constants / bias in LDS
    for (int t = threadIdx.x; t < KPK * CIN * COUT; t += blockDim.x) sW[t] = weights[t];
    if (threadIdx.x < COUT) sB[threadIdx.x] = bias[threadIdx.x];
    if (threadIdx.x < KPK) {
        const float L2E = 1.44269504088896f;   // log2(e)
        float kx = kpts[threadIdx.x * 3 + 0];
        float ky = kpts[threadIdx.x * 3 + 1];
        float kz = kpts[threadIdx.x * 3 + 2];
        float ck = kx * kx + ky * ky + kz * kz;
        // influence = exp(-(|r|^2 - 2 r.kp + |kp|^2)/0.005)
        //           = exp2( C0*|r|^2 + (400*L2E)*r.kp + (-200*L2E)*|kp|^2 )
        sKC[threadIdx.x] = make_float4(400.0f * L2E * kx,
                                       400.0f * L2E * ky,
                                       400.0f * L2E * kz,
                                       -200.0f * L2E * ck);
    }
    __syncthreads();

    int gid = blockIdx.x * blockDim.x + threadIdx.x;
    int pt  = gid >> 2;        // point id
    int sub = gid & 3;         // lane-slice within the point
    if (pt >= n) return;

    float px = points[pt * 3 + 0];
    float py = points[pt * 3 + 1];
    float pz = points[pt * 3 + 2];

    // 8 contiguous neighbor indices per lane -> two coalesced int4 loads
    const int* nb = nbr + (size_t)pt * NH + sub * HPL;
    int4 idxa = *reinterpret_cast<const int4*>(nb);
    int4 idxb = *reinterpret_cast<const int4*>(nb + 4);
    int js[HPL] = {idxa.x, idxa.y, idxa.z, idxa.w,
                   idxb.x, idxb.y, idxb.z, idxb.w};

    float acc[KPK][CIN];
    #pragma unroll
    for (int k = 0; k < KPK; ++k) { acc[k][0] = 0.f; acc[k][1] = 0.f; acc[k][2] = 0.f; }

    const float C0 = -200.0f * 1.44269504088896f;   // -200*log2(e)

    #pragma unroll
    for (int t = 0; t < HPL; ++t) {
        int j = js[t];
        float qx = points[j * 3 + 0];
        float qy = points[j * 3 + 1];
        float qz = points[j * 3 + 2];
        float rx = qx - px, ry = qy - py, rz = qz - pz;
        float e0 = C0 * (rx * rx + ry * ry + rz * rz);
        #pragma unroll
        for (int k = 0; k < KPK; ++k) {
            float4 kc = sKC[k];
            float e = e0 + kc.w;
            e = fmaf(rx, kc.x, e);
            e = fmaf(ry, kc.y, e);
            e = fmaf(rz, kc.z, e);
            float infl = exp2f(e);
            // features are the neighbor coords themselves
            acc[k][0] = fmaf(infl, qx, acc[k][0]);
            acc[k][1] = fmaf(infl, qy, acc[k][1]);
            acc[k][2] = fmaf(infl, qz, acc[k][2]);
        }
    }

    // butterfly-reduce the 45 accumulators across the 4 lanes of this point
    // (reduce acc BEFORE slicing the epilogue — same meaning in every lane)
    #pragma unroll
    for (int m = 1; m < LPP; m <<= 1) {
        #pragma unroll
        for (int k = 0; k < KPK; ++k) {
            acc[k][0] += __shfl_xor(acc[k][0], m, 64);
            acc[k][1] += __shfl_xor(acc[k][1], m, 64);
            acc[k][2] += __shfl_xor(acc[k][2], m, 64);
        }
    }

    // epilogue: each lane produces 8 of the 32 outputs
    int d0 = sub * 8;
    float4 o0 = *reinterpret_cast<const float4*>(sB + d0);
    float4 o1 = *reinterpret_cast<const float4*>(sB + d0 + 4);
    #pragma unroll
    for (int k = 0; k < KPK; ++k) {
        #pragma unroll
        for (int c = 0; c < CIN; ++c) {
            float a = acc[k][c];
            const float* w = sW + (k * CIN + c) * COUT + d0;
            float4 w0 = *reinterpret_cast<const float4*>(w);
            float4 w1 = *reinterpret_cast<const float4*>(w + 4);
            o0.x = fmaf(a, w0.x, o0.x);
            o0.y = fmaf(a, w0.y, o0.y);
            o0.z = fmaf(a, w0.z, o0.z);
            o0.w = fmaf(a, w0.w, o0.w);
            o1.x = fmaf(a, w1.x, o1.x);
            o1.y = fmaf(a, w1.y, o1.y);
            o1.z = fmaf(a, w1.z, o1.z);
            o1.w = fmaf(a, w1.w, o1.w);
        }
    }

    float* op = out + (size_t)pt * COUT + d0;
    *reinterpret_cast<float4*>(op)     = o0;
    *reinterpret_cast<float4*>(op + 4) = o1;
}

extern "C" void kernel_launch(void* const* d_in, const int* in_sizes, int n_in,
                              void* d_out, int out_size, void* d_ws, size_t ws_size,
                              hipStream_t stream) {
    const float* points  = (const float*)d_in[0];
    const int*   nbr     = (const int*)d_in[1];
    const float* kpts    = (const float*)d_in[2];
    const float* weights = (const float*)d_in[3];
    const float* bias    = (const float*)d_in[4];
    float* out = (float*)d_out;

    int n = in_sizes[0] / 3;
    int total = n * LPP;
    int threads = 256;
    int blocks = (total + threads - 1) / threads;
    kpconv_kernel<<<blocks, threads, 0, stream>>>(points, nbr, kpts, weights, bias, out, n);
}